// Round 13
// baseline (106.795 us; speedup 1.0000x reference)
//
#include <hip/hip_runtime.h>
#include <math.h>

#define AFWD 0.999f
#define ONE_MINUS_A (1.0f - 0.999f)
#define KCOEF (0.999f * (1.0f - 0.999f))
#define EPSV 1e-5f

typedef float floatx4 __attribute__((ext_vector_type(4)));

#define TPB   512      // threads per block
#define BCOLS 16       // scalar columns per block
#define BC4   4        // float4 columns per block  (TPB/BC4 = 128 subs)
#define MAXSUB 128     // max sub-chunks per column

// ===========================================================================
// Single-dispatch, block-local online normalization.
// Block = 16-column stripe x all N rows (512KB slab). 512 threads =
// 128 sub-chunks x 4 float4-cols; a wave's 4-lane clusters each read a fully
// used 64B line. Phase A: per-thread sub-chunk summary (B,T,S) -> LDS.
// Phase B (all in LDS, proven R6/R10 algebra):
//   compose 16 chunks -> super;  walk supers with (m,var);  re-expand.
// Phase C: exact replay from per-sub-chunk start states, NT store.
// No global scratch, no cross-block sync, no atomics -> avoids the
// coop/lookback cache-poisoning (R4/R9/R11: 0.9-1.5 TB/s) entirely.
//   apply:   sum = S - 2*ceg*M*T + M^2*Sgg ; V' = A*V+KCOEF*sum ; M' = A*M+B
//   compose: S <- A*S + s2 - 2*ceg*B*t2 + Sgg*B^2 ; T <- T + t2 - G*B ;
//            B <- A*B + b2
// ===========================================================================
__global__ __launch_bounds__(TPB) void
stripe_cn(const float* __restrict__ x, const float* __restrict__ m,
          const float* __restrict__ var, float* __restrict__ out,
          int L4, int CH, int SUBS, int GSUP,
          float A, float c_eg, float Sgg, float G,
          float Asup, float c_sup, float Sggsup) {
  __shared__ float sB[MAXSUB][BCOLS], sS[MAXSUB][BCOLS], sT[MAXSUB][BCOLS];
  __shared__ float sM[MAXSUB][BCOLS], sV[MAXSUB][BCOLS];
  __shared__ float gB[8][BCOLS], gS[8][BCOLS], gT[8][BCOLS];
  __shared__ float gM[8][BCOLS], gV[8][BCOLS];

  int tid  = threadIdx.x;
  int c4   = tid & (BC4 - 1);    // float4 col within block
  int sub  = tid >> 2;           // sub-chunk [0,128)
  int col4 = blockIdx.x * BC4 + c4;
  const floatx4* xv = (const floatx4*)x;
  int base = sub * CH * L4 + col4;
  bool active = (sub < SUBS);

  // ---------------- phase A: sub-chunk summaries ----------------
  if (active) {
    float mu[4] = {0.f, 0.f, 0.f, 0.f};
    float sv[4] = {0.f, 0.f, 0.f, 0.f};
    float tv[4] = {0.f, 0.f, 0.f, 0.f};
#pragma unroll 4
    for (int i = 0; i < CH; ++i) {
      floatx4 v = xv[base + i * L4];
#pragma unroll
      for (int k = 0; k < 4; ++k) {
        float e = v[k] - mu[k];
        sv[k] = fmaf(AFWD, sv[k], e * e);
        tv[k] += e;
        mu[k] = fmaf(ONE_MINUS_A, e, mu[k]);
      }
    }
#pragma unroll
    for (int k = 0; k < 4; ++k) {
      sB[sub][c4 * 4 + k] = mu[k];
      sS[sub][c4 * 4 + k] = sv[k];
      sT[sub][c4 * 4 + k] = tv[k];
    }
  }
  __syncthreads();

  // ---------------- phase B1: compose 16 chunks -> super ----------------
  if (tid < GSUP * BCOLS) {
    int col = tid & (BCOLS - 1);
    int g   = tid / BCOLS;
    float B = 0.f, T = 0.f, S = 0.f;
#pragma unroll 4
    for (int k = 0; k < 16; ++k) {
      int su = g * 16 + k;
      float b2 = sB[su][col];
      float s2 = sS[su][col];
      float t2 = sT[su][col];
      S = fmaf(A, S, fmaf(Sgg * B, B, fmaf(-2.0f * c_eg * B, t2, s2)));
      T = fmaf(-G, B, T + t2);
      B = fmaf(A, B, b2);
    }
    gB[g][col] = B;
    gS[g][col] = S;
    gT[g][col] = T;
  }
  __syncthreads();

  // ---------------- phase B2: walk supers with (m,var) ----------------
  if (tid < BCOLS) {
    int col = tid;
    int l = blockIdx.x * BCOLS + col;
    float M = m[l];
    float V = var[l];
    for (int g = 0; g < GSUP; ++g) {
      gM[g][col] = M;
      gV[g][col] = V;
      float b = gB[g][col];
      float s = gS[g][col];
      float t = gT[g][col];
      float sum = fmaf(M * M, Sggsup, fmaf(-2.0f * c_sup * M, t, s));
      V = fmaf(Asup, V, KCOEF * sum);
      M = fmaf(Asup, M, b);
    }
  }
  __syncthreads();

  // ---------------- phase B3: re-expand to chunk-start states ----------
  if (tid < GSUP * BCOLS) {
    int col = tid & (BCOLS - 1);
    int g   = tid / BCOLS;
    float M = gM[g][col];
    float V = gV[g][col];
#pragma unroll 4
    for (int k = 0; k < 16; ++k) {
      int su = g * 16 + k;
      sM[su][col] = M;
      sV[su][col] = V;
      float b = sB[su][col];
      float s = sS[su][col];
      float t = sT[su][col];
      float sum = fmaf(M * M, Sgg, fmaf(-2.0f * c_eg * M, t, s));
      V = fmaf(A, V, KCOEF * sum);
      M = fmaf(A, M, b);
    }
  }
  __syncthreads();

  // ---------------- phase C: exact replay + NT store ----------------
  if (active) {
    floatx4* ov = (floatx4*)out;
    float M[4], V[4];
#pragma unroll
    for (int k = 0; k < 4; ++k) {
      M[k] = sM[sub][c4 * 4 + k];
      V[k] = sV[sub][c4 * 4 + k];
    }
#pragma unroll 4
    for (int i = 0; i < CH; ++i) {
      floatx4 v = xv[base + i * L4];
      floatx4 oe;
#pragma unroll
      for (int k = 0; k < 4; ++k) {
        float d = v[k] - M[k];
        oe[k] = d * rsqrtf(V[k] + EPSV);
        V[k] = fmaf(AFWD, V[k], KCOEF * (d * d));
        M[k] = fmaf(ONE_MINUS_A, d, M[k]);
      }
      __builtin_nontemporal_store(oe, &ov[base + i * L4]);
    }
  }
}

extern "C" void kernel_launch(void* const* d_in, const int* in_sizes, int n_in,
                              void* d_out, int out_size, void* d_ws, size_t ws_size,
                              hipStream_t stream) {
  const float* x   = (const float*)d_in[0];
  const float* m   = (const float*)d_in[1];
  const float* var = (const float*)d_in[2];
  float* out = (float*)d_out;

  int L  = in_sizes[1];          // 4096
  int N  = in_sizes[0] / L;      // 8192
  int L4 = L / 4;

  // SUBS sub-chunks per column (<=128, multiple of 16 for the hierarchy).
  int SUBS = MAXSUB;
  while (SUBS > 16 && (N % SUBS) != 0) SUBS >>= 1;
  int CH   = N / SUBS;           // rows per sub-chunk (64)
  int GSUP = SUBS / 16;          // supers (8)

  double a = 0.999;
  float A    = (float)pow(a, (double)CH);
  float c_eg = (float)pow(a, (double)(CH - 1));
  float Sgg  = (float)(pow(a, (double)(CH - 1)) * (1.0 - pow(a, (double)CH)) / (1.0 - a));
  float G    = (float)((1.0 - pow(a, (double)CH)) / (1.0 - a));
  double nS = 16.0 * CH;
  float Asup   = (float)pow(a, nS);
  float c_sup  = (float)pow(a, nS - 1.0);
  float Sggsup = (float)(pow(a, nS - 1.0) * (1.0 - pow(a, nS)) / (1.0 - a));

  int blocks = L4 / BC4;         // 256 stripe blocks
  stripe_cn<<<blocks, TPB, 0, stream>>>(x, m, var, out, L4, CH, SUBS, GSUP,
                                        A, c_eg, Sgg, G, Asup, c_sup, Sggsup);
}

// Round 14
// 80.112 us; speedup vs baseline: 1.3331x; 1.3331x over previous
//
#include <hip/hip_runtime.h>
#include <math.h>

#define AFWD 0.999f
#define ONE_MINUS_A (1.0f - 0.999f)
#define KCOEF (0.999f * (1.0f - 0.999f))
#define EPSV 1e-5f

typedef float floatx4 __attribute__((ext_vector_type(4)));

// ---------------------------------------------------------------------------
// Pass A (proven R10): per (chunk c, col4) local summaries with chunk-start
// M=0. Bmu = local mu after CH steps, Te = sum e_i, See = sum a^{CH-1-i} e_i^2
// ---------------------------------------------------------------------------
__global__ __launch_bounds__(256) void
passA(const float* __restrict__ x, float* __restrict__ Bmu,
      float* __restrict__ See, float* __restrict__ Te, int L4, int CH) {
  int idx  = blockIdx.x * blockDim.x + threadIdx.x;
  int col4 = idx % L4;
  int c    = idx / L4;
  const floatx4* xv = (const floatx4*)x;
  int base = c * CH * L4 + col4;

  float mu[4] = {0.f, 0.f, 0.f, 0.f};
  float s[4]  = {0.f, 0.f, 0.f, 0.f};
  float t[4]  = {0.f, 0.f, 0.f, 0.f};
#pragma unroll 4
  for (int i = 0; i < CH; ++i) {
    floatx4 v = xv[base + i * L4];
#pragma unroll
    for (int k = 0; k < 4; ++k) {
      float e = v[k] - mu[k];
      s[k] = fmaf(AFWD, s[k], e * e);
      t[k] += e;
      mu[k] = fmaf(ONE_MINUS_A, e, mu[k]);
    }
  }
  int o = c * L4 + col4;
  floatx4 om = {mu[0], mu[1], mu[2], mu[3]};
  floatx4 os = {s[0], s[1], s[2], s[3]};
  floatx4 ot = {t[0], t[1], t[2], t[3]};
  ((floatx4*)Bmu)[o] = om;
  ((floatx4*)See)[o] = os;
  ((floatx4*)Te)[o]  = ot;
}

// ---------------------------------------------------------------------------
// Pass B (proven R10): block = 8 super-chunk slots x 32 cols; block-local
// hierarchical resolution, zero cross-block sync.
// ---------------------------------------------------------------------------
__global__ __launch_bounds__(256) void
passBfused(const float* __restrict__ m, const float* __restrict__ var,
           const float* __restrict__ Bmu, const float* __restrict__ See,
           const float* __restrict__ Te, float* __restrict__ Ms,
           float* __restrict__ Vs, int L, int SUB, int GS,
           float A, float c_eg, float Sgg, float G,
           float Asup, float c_sup, float Sggsup) {
  __shared__ float Bs[8][32], Ss[8][32], Ts[8][32];
  __shared__ float MgL[8][32], VgL[8][32];

  int g  = threadIdx.x >> 5;
  int lc = threadIdx.x & 31;
  int l  = blockIdx.x * 32 + lc;

  {
    int base = g * SUB * L + l;
    float B = 0.f, T = 0.f, S = 0.f;
#pragma unroll 4
    for (int k = 0; k < SUB; ++k) {
      int o = base + k * L;
      float b2 = Bmu[o];
      float s2 = See[o];
      float t2 = Te[o];
      S = fmaf(A, S, fmaf(Sgg * B, B, fmaf(-2.0f * c_eg * B, t2, s2)));
      T = fmaf(-G, B, T + t2);
      B = fmaf(A, B, b2);
    }
    Bs[g][lc] = B;
    Ss[g][lc] = S;
    Ts[g][lc] = T;
  }

  __syncthreads();

  if (threadIdx.x < 32) {
    float M = m[l];
    float V = var[l];
#pragma unroll
    for (int gg = 0; gg < 8; ++gg) {
      if (gg >= GS) break;
      MgL[gg][lc] = M;
      VgL[gg][lc] = V;
      float b = Bs[gg][lc];
      float s = Ss[gg][lc];
      float t = Ts[gg][lc];
      float sum = fmaf(M * M, Sggsup, fmaf(-2.0f * c_sup * M, t, s));
      V = fmaf(Asup, V, KCOEF * sum);
      M = fmaf(Asup, M, b);
    }
  }

  __syncthreads();

  {
    float M = MgL[g][lc];
    float V = VgL[g][lc];
    int base = g * SUB * L + l;
#pragma unroll 4
    for (int k = 0; k < SUB; ++k) {
      int o = base + k * L;
      Ms[o] = M;
      Vs[o] = V;
      float b = Bmu[o];
      float s = See[o];
      float t = Te[o];
      float sum = fmaf(M * M, Sgg, fmaf(-2.0f * c_eg * M, t, s));
      V = fmaf(A, V, KCOEF * sum);
      M = fmaf(A, M, b);
    }
  }
}

// ---------------------------------------------------------------------------
// Pass C: replay exact recurrence from (M_c, V_c).
// CHANGES vs R10 (this round's experiment):
//   - x read via nontemporal LOADS  (x dead after this pass; keeps L2 clean,
//     reads served from L3 where x resides per R9/R12)
//   - out via NORMAL stores         (the path the 7.16 TB/s fill kernel uses)
// ---------------------------------------------------------------------------
__global__ __launch_bounds__(256) void
passC(const float* __restrict__ x, const float* __restrict__ Ms,
      const float* __restrict__ Vs, float* __restrict__ out, int L4, int CH) {
  int idx  = blockIdx.x * blockDim.x + threadIdx.x;
  int col4 = idx % L4;
  int c    = idx / L4;
  const floatx4* xv = (const floatx4*)x;
  floatx4* ov = (floatx4*)out;
  int base = c * CH * L4 + col4;

  int o = c * L4 + col4;
  floatx4 m4 = ((const floatx4*)Ms)[o];
  floatx4 v4 = ((const floatx4*)Vs)[o];
  float mu[4] = {m4[0], m4[1], m4[2], m4[3]};
  float vv[4] = {v4[0], v4[1], v4[2], v4[3]};
#pragma unroll 4
  for (int i = 0; i < CH; ++i) {
    floatx4 v = __builtin_nontemporal_load(&xv[base + i * L4]);
    floatx4 oe;
#pragma unroll
    for (int k = 0; k < 4; ++k) {
      float d = v[k] - mu[k];
      oe[k] = d * rsqrtf(vv[k] + EPSV);
      vv[k] = fmaf(AFWD, vv[k], KCOEF * (d * d));
      mu[k] = fmaf(ONE_MINUS_A, d, mu[k]);
    }
    ov[base + i * L4] = oe;
  }
}

extern "C" void kernel_launch(void* const* d_in, const int* in_sizes, int n_in,
                              void* d_out, int out_size, void* d_ws, size_t ws_size,
                              hipStream_t stream) {
  const float* x   = (const float*)d_in[0];
  const float* m   = (const float*)d_in[1];
  const float* var = (const float*)d_in[2];
  float* out = (float*)d_out;

  int L  = in_sizes[1];          // 4096
  int N  = in_sizes[0] / L;      // 8192
  int L4 = L / 4;

  int C = 128;
  while (C > 1 &&
         ((size_t)5 * C * L * sizeof(float) > ws_size || (N % C) != 0))
    C >>= 1;
  int CH = N / C;
  int SUB = (C >= 16) ? 16 : C;
  int GS  = C / SUB;   // <= 8 for passBfused LDS

  double a = 0.999;
  float A    = (float)pow(a, (double)CH);
  float c_eg = (float)pow(a, (double)(CH - 1));
  float Sgg  = (float)(pow(a, (double)(CH - 1)) * (1.0 - pow(a, (double)CH)) / (1.0 - a));
  float G    = (float)((1.0 - pow(a, (double)CH)) / (1.0 - a));
  double nS = (double)SUB * CH;
  float Asup   = (float)pow(a, nS);
  float c_sup  = (float)pow(a, nS - 1.0);
  float Sggsup = (float)(pow(a, nS - 1.0) * (1.0 - pow(a, nS)) / (1.0 - a));

  float* ws  = (float*)d_ws;
  size_t CL  = (size_t)C * L;
  float* Bmu = ws;
  float* See = ws + CL;
  float* Te  = ws + 2 * CL;
  float* Ms  = ws + 3 * CL;
  float* Vs  = ws + 4 * CL;

  int gridBlocks = (C * L4) / 256;
  passA<<<gridBlocks, 256, 0, stream>>>(x, Bmu, See, Te, L4, CH);
  passBfused<<<L / 32, 256, 0, stream>>>(m, var, Bmu, See, Te, Ms, Vs, L,
                                         SUB, GS, A, c_eg, Sgg, G,
                                         Asup, c_sup, Sggsup);
  passC<<<gridBlocks, 256, 0, stream>>>(x, Ms, Vs, out, L4, CH);
}

// Round 15
// 76.840 us; speedup vs baseline: 1.3898x; 1.0426x over previous
//
#include <hip/hip_runtime.h>
#include <math.h>

#define AFWD 0.999f
#define ONE_MINUS_A (1.0f - 0.999f)
#define KCOEF (0.999f * (1.0f - 0.999f))
#define EPSV 1e-5f

typedef float floatx4 __attribute__((ext_vector_type(4)));

// ---------------------------------------------------------------------------
// Pass A (R10 structure, unroll 8 for deeper MLP): per (chunk c, col4) local
// summaries with chunk-start M=0.
// ---------------------------------------------------------------------------
__global__ __launch_bounds__(256) void
passA(const float* __restrict__ x, float* __restrict__ Bmu,
      float* __restrict__ See, float* __restrict__ Te, int L4, int CH) {
  int idx  = blockIdx.x * blockDim.x + threadIdx.x;
  int col4 = idx % L4;
  int c    = idx / L4;
  const floatx4* xv = (const floatx4*)x;
  int base = c * CH * L4 + col4;

  float mu[4] = {0.f, 0.f, 0.f, 0.f};
  float s[4]  = {0.f, 0.f, 0.f, 0.f};
  float t[4]  = {0.f, 0.f, 0.f, 0.f};
#pragma unroll 8
  for (int i = 0; i < CH; ++i) {
    floatx4 v = xv[base + i * L4];
#pragma unroll
    for (int k = 0; k < 4; ++k) {
      float e = v[k] - mu[k];
      s[k] = fmaf(AFWD, s[k], e * e);
      t[k] += e;
      mu[k] = fmaf(ONE_MINUS_A, e, mu[k]);
    }
  }
  int o = c * L4 + col4;
  floatx4 om = {mu[0], mu[1], mu[2], mu[3]};
  floatx4 os = {s[0], s[1], s[2], s[3]};
  floatx4 ot = {t[0], t[1], t[2], t[3]};
  ((floatx4*)Bmu)[o] = om;
  ((floatx4*)See)[o] = os;
  ((floatx4*)Te)[o]  = ot;
}

// ---------------------------------------------------------------------------
// Pass B (proven R10): block = 8 super-chunk slots x 32 cols; block-local
// hierarchical resolution, zero cross-block sync.
// ---------------------------------------------------------------------------
__global__ __launch_bounds__(256) void
passBfused(const float* __restrict__ m, const float* __restrict__ var,
           const float* __restrict__ Bmu, const float* __restrict__ See,
           const float* __restrict__ Te, float* __restrict__ Ms,
           float* __restrict__ Vs, int L, int SUB, int GS,
           float A, float c_eg, float Sgg, float G,
           float Asup, float c_sup, float Sggsup) {
  __shared__ float Bs[8][32], Ss[8][32], Ts[8][32];
  __shared__ float MgL[8][32], VgL[8][32];

  int g  = threadIdx.x >> 5;
  int lc = threadIdx.x & 31;
  int l  = blockIdx.x * 32 + lc;

  {
    int base = g * SUB * L + l;
    float B = 0.f, T = 0.f, S = 0.f;
#pragma unroll 4
    for (int k = 0; k < SUB; ++k) {
      int o = base + k * L;
      float b2 = Bmu[o];
      float s2 = See[o];
      float t2 = Te[o];
      S = fmaf(A, S, fmaf(Sgg * B, B, fmaf(-2.0f * c_eg * B, t2, s2)));
      T = fmaf(-G, B, T + t2);
      B = fmaf(A, B, b2);
    }
    Bs[g][lc] = B;
    Ss[g][lc] = S;
    Ts[g][lc] = T;
  }

  __syncthreads();

  if (threadIdx.x < 32) {
    float M = m[l];
    float V = var[l];
#pragma unroll
    for (int gg = 0; gg < 8; ++gg) {
      if (gg >= GS) break;
      MgL[gg][lc] = M;
      VgL[gg][lc] = V;
      float b = Bs[gg][lc];
      float s = Ss[gg][lc];
      float t = Ts[gg][lc];
      float sum = fmaf(M * M, Sggsup, fmaf(-2.0f * c_sup * M, t, s));
      V = fmaf(Asup, V, KCOEF * sum);
      M = fmaf(Asup, M, b);
    }
  }

  __syncthreads();

  {
    float M = MgL[g][lc];
    float V = VgL[g][lc];
    int base = g * SUB * L + l;
#pragma unroll 4
    for (int k = 0; k < SUB; ++k) {
      int o = base + k * L;
      Ms[o] = M;
      Vs[o] = V;
      float b = Bmu[o];
      float s = See[o];
      float t = Te[o];
      float sum = fmaf(M * M, Sgg, fmaf(-2.0f * c_eg * M, t, s));
      V = fmaf(A, V, KCOEF * sum);
      M = fmaf(A, M, b);
    }
  }
}

// ---------------------------------------------------------------------------
// Pass C (R10 configuration: NORMAL loads so x hits L3, NT stores so out
// doesn't churn L2/L3; unroll 8 for deeper MLP).
// ---------------------------------------------------------------------------
__global__ __launch_bounds__(256) void
passC(const float* __restrict__ x, const float* __restrict__ Ms,
      const float* __restrict__ Vs, float* __restrict__ out, int L4, int CH) {
  int idx  = blockIdx.x * blockDim.x + threadIdx.x;
  int col4 = idx % L4;
  int c    = idx / L4;
  const floatx4* xv = (const floatx4*)x;
  floatx4* ov = (floatx4*)out;
  int base = c * CH * L4 + col4;

  int o = c * L4 + col4;
  floatx4 m4 = ((const floatx4*)Ms)[o];
  floatx4 v4 = ((const floatx4*)Vs)[o];
  float mu[4] = {m4[0], m4[1], m4[2], m4[3]};
  float vv[4] = {v4[0], v4[1], v4[2], v4[3]};
#pragma unroll 8
  for (int i = 0; i < CH; ++i) {
    floatx4 v = xv[base + i * L4];
    floatx4 oe;
#pragma unroll
    for (int k = 0; k < 4; ++k) {
      float d = v[k] - mu[k];
      oe[k] = d * rsqrtf(vv[k] + EPSV);
      vv[k] = fmaf(AFWD, vv[k], KCOEF * (d * d));
      mu[k] = fmaf(ONE_MINUS_A, d, mu[k]);
    }
    __builtin_nontemporal_store(oe, &ov[base + i * L4]);
  }
}

extern "C" void kernel_launch(void* const* d_in, const int* in_sizes, int n_in,
                              void* d_out, int out_size, void* d_ws, size_t ws_size,
                              hipStream_t stream) {
  const float* x   = (const float*)d_in[0];
  const float* m   = (const float*)d_in[1];
  const float* var = (const float*)d_in[2];
  float* out = (float*)d_out;

  int L  = in_sizes[1];          // 4096
  int N  = in_sizes[0] / L;      // 8192
  int L4 = L / 4;

  int C = 128;
  while (C > 1 &&
         ((size_t)5 * C * L * sizeof(float) > ws_size || (N % C) != 0))
    C >>= 1;
  int CH = N / C;
  int SUB = (C >= 16) ? 16 : C;
  int GS  = C / SUB;   // <= 8 for passBfused LDS

  double a = 0.999;
  float A    = (float)pow(a, (double)CH);
  float c_eg = (float)pow(a, (double)(CH - 1));
  float Sgg  = (float)(pow(a, (double)(CH - 1)) * (1.0 - pow(a, (double)CH)) / (1.0 - a));
  float G    = (float)((1.0 - pow(a, (double)CH)) / (1.0 - a));
  double nS = (double)SUB * CH;
  float Asup   = (float)pow(a, nS);
  float c_sup  = (float)pow(a, nS - 1.0);
  float Sggsup = (float)(pow(a, nS - 1.0) * (1.0 - pow(a, nS)) / (1.0 - a));

  float* ws  = (float*)d_ws;
  size_t CL  = (size_t)C * L;
  float* Bmu = ws;
  float* See = ws + CL;
  float* Te  = ws + 2 * CL;
  float* Ms  = ws + 3 * CL;
  float* Vs  = ws + 4 * CL;

  int gridBlocks = (C * L4) / 256;
  passA<<<gridBlocks, 256, 0, stream>>>(x, Bmu, See, Te, L4, CH);
  passBfused<<<L / 32, 256, 0, stream>>>(m, var, Bmu, See, Te, Ms, Vs, L,
                                         SUB, GS, A, c_eg, Sgg, G,
                                         Asup, c_sup, Sggsup);
  passC<<<gridBlocks, 256, 0, stream>>>(x, Ms, Vs, out, L4, CH);
}